// Round 1
// baseline (611.635 us; speedup 1.0000x reference)
//
#include <hip/hip_runtime.h>
#include <math.h>

// Problem constants (fixed by setup_inputs)
constexpr int Bc  = 32;     // batch
constexpr int Dc  = 256;    // word feature dim
constexpr int Tc  = 32;     // seq len
constexpr int DHc = 128;    // image feature dim
constexpr int Nc  = 16384;  // H*W = 128*128

// Stage 1: values[b,k,t] = bias[k] + sum_d W[k,d] * wf[b,d,t]
__global__ __launch_bounds__(256) void values_kernel(
    const float* __restrict__ wf, const float* __restrict__ Wm,
    const float* __restrict__ bias, float* __restrict__ values)
{
    int id = blockIdx.x * 256 + threadIdx.x;    // 131072 total
    int t = id & (Tc - 1);
    int k = (id >> 5) & (DHc - 1);
    int b = id >> 12;
    const float* wrow = Wm + (size_t)k * Dc;
    const float* wfp  = wf + (size_t)b * Dc * Tc + t;
    float acc = bias[k];
    #pragma unroll 8
    for (int d = 0; d < Dc; ++d)
        acc = fmaf(wrow[d], wfp[(size_t)d * Tc], acc);
    values[id] = acc;   // layout [b][k][t] contiguous
}

// Stage 2: per 512-pixel tile of one batch:
//   S[n,t] = sum_k q[k,n]*V[k,t]; softmax over t (masked); attn[k,n] = sum_t V[k,t]*p[n,t]
__global__ __launch_bounds__(256) void attn_kernel(
    const float* __restrict__ img, const float* __restrict__ values,
    const int* __restrict__ mask, float* __restrict__ attn,
    float* __restrict__ coeff)
{
    __shared__ float Vs[DHc * Tc];   // 16 KB, [k][t]
    __shared__ float mneg[Tc];       // 0 or -inf additive mask

    const int tid  = threadIdx.x;
    const int b    = blockIdx.x >> 5;    // 32 tiles per batch
    const int tile = blockIdx.x & 31;

    {   // cooperative V load: 4096 floats via 256 threads * 4 float4
        const float4* vg = (const float4*)(values + (size_t)b * DHc * Tc);
        float4* vs = (float4*)Vs;
        #pragma unroll
        for (int i = 0; i < 4; ++i) vs[i * 256 + tid] = vg[i * 256 + tid];
    }
    if (tid < Tc) mneg[tid] = mask[b * Tc + tid] ? -INFINITY : 0.0f;
    __syncthreads();

    const int n = tile * 512 + tid * 2;  // this thread's pixel pair
    const float* qp = img + (size_t)b * DHc * Nc + n;

    float s0[Tc], s1[Tc];
    #pragma unroll
    for (int t = 0; t < Tc; ++t) { s0[t] = 0.0f; s1[t] = 0.0f; }

    // ---- QK^T : S[n,t] over k=0..127 ----
    #pragma unroll 2
    for (int k = 0; k < DHc; ++k) {
        const float2 q = *(const float2*)(qp + (size_t)k * Nc);  // coalesced 8B
        const float4* vrow = (const float4*)(Vs + k * Tc);       // wave-uniform (broadcast)
        #pragma unroll
        for (int tt = 0; tt < 8; ++tt) {
            const float4 v = vrow[tt];
            s0[4*tt+0] = fmaf(q.x, v.x, s0[4*tt+0]);
            s0[4*tt+1] = fmaf(q.x, v.y, s0[4*tt+1]);
            s0[4*tt+2] = fmaf(q.x, v.z, s0[4*tt+2]);
            s0[4*tt+3] = fmaf(q.x, v.w, s0[4*tt+3]);
            s1[4*tt+0] = fmaf(q.y, v.x, s1[4*tt+0]);
            s1[4*tt+1] = fmaf(q.y, v.y, s1[4*tt+1]);
            s1[4*tt+2] = fmaf(q.y, v.z, s1[4*tt+2]);
            s1[4*tt+3] = fmaf(q.y, v.w, s1[4*tt+3]);
        }
    }

    // ---- masked softmax over t (in registers) ----
    float m0 = -INFINITY, m1 = -INFINITY;
    #pragma unroll
    for (int t = 0; t < Tc; ++t) {
        s0[t] += mneg[t]; s1[t] += mneg[t];
        m0 = fmaxf(m0, s0[t]); m1 = fmaxf(m1, s1[t]);
    }
    float sum0 = 0.0f, sum1 = 0.0f;
    #pragma unroll
    for (int t = 0; t < Tc; ++t) {
        s0[t] = __expf(s0[t] - m0); sum0 += s0[t];
        s1[t] = __expf(s1[t] - m1); sum1 += s1[t];
    }
    const float inv0 = 1.0f / sum0, inv1 = 1.0f / sum1;
    #pragma unroll
    for (int t = 0; t < Tc; ++t) { s0[t] *= inv0; s1[t] *= inv1; }

    // ---- write coefficients [B,N,T]: 64 contiguous floats per thread ----
    {
        float4* cp = (float4*)(coeff + ((size_t)b * Nc + n) * Tc);
        #pragma unroll
        for (int tt = 0; tt < 8; ++tt)
            cp[tt] = make_float4(s0[4*tt+0], s0[4*tt+1], s0[4*tt+2], s0[4*tt+3]);
        #pragma unroll
        for (int tt = 0; tt < 8; ++tt)
            cp[8+tt] = make_float4(s1[4*tt+0], s1[4*tt+1], s1[4*tt+2], s1[4*tt+3]);
    }

    // ---- P·V^T : attn[k,n] = sum_t V[k,t] * p[n,t] ----
    float* ap = attn + (size_t)b * DHc * Nc + n;
    #pragma unroll 2
    for (int k = 0; k < DHc; ++k) {
        const float4* vrow = (const float4*)(Vs + k * Tc);
        float a0 = 0.f, b0 = 0.f, c0 = 0.f, d0 = 0.f;
        float a1 = 0.f, b1 = 0.f, c1 = 0.f, d1 = 0.f;
        #pragma unroll
        for (int tt = 0; tt < 8; ++tt) {
            const float4 v = vrow[tt];
            a0 = fmaf(v.x, s0[4*tt+0], a0);
            b0 = fmaf(v.y, s0[4*tt+1], b0);
            c0 = fmaf(v.z, s0[4*tt+2], c0);
            d0 = fmaf(v.w, s0[4*tt+3], d0);
            a1 = fmaf(v.x, s1[4*tt+0], a1);
            b1 = fmaf(v.y, s1[4*tt+1], b1);
            c1 = fmaf(v.z, s1[4*tt+2], c1);
            d1 = fmaf(v.w, s1[4*tt+3], d1);
        }
        *(float2*)(ap + (size_t)k * Nc) =
            make_float2((a0 + b0) + (c0 + d0), (a1 + b1) + (c1 + d1));
    }
}

extern "C" void kernel_launch(void* const* d_in, const int* in_sizes, int n_in,
                              void* d_out, int out_size, void* d_ws, size_t ws_size,
                              hipStream_t stream)
{
    const float* wf   = (const float*)d_in[0];  // [B,D,T]
    const float* img  = (const float*)d_in[1];  // [B,Dh,H,W]
    const int*   msk  = (const int*)d_in[2];    // [B,T]
    const float* Wm   = (const float*)d_in[3];  // [Dh,D]
    const float* bias = (const float*)d_in[4];  // [Dh]

    float* attn  = (float*)d_out;                        // [B,Dh,N]
    float* coeff = attn + (size_t)Bc * DHc * Nc;         // [B,N,T]
    float* vals  = (float*)d_ws;                         // [B,Dh,T] scratch (512 KB)

    values_kernel<<<(Bc * DHc * Tc) / 256, 256, 0, stream>>>(wf, Wm, bias, vals);
    attn_kernel<<<(Bc * Nc) / 512, 256, 0, stream>>>(img, vals, msk, attn, coeff);
}